// Round 15
// baseline (942.750 us; speedup 1.0000x reference)
//
#include <hip/hip_runtime.h>

#define NIN 1024
#define IVL 64
#define ONUM 64
#define LVL 32
#define OLSZ 2048  // ONUM*LVL

typedef __attribute__((ext_vector_type(4))) float f32x4;
typedef __attribute__((ext_vector_type(4))) unsigned u32x4;
typedef __attribute__((ext_vector_type(8))) short short8;

static __device__ __forceinline__ unsigned short f2bf(float f) {
  unsigned u = __builtin_bit_cast(unsigned, f);
  u += 0x7fffu + ((u >> 16) & 1u);
  return (unsigned short)(u >> 16);
}
static __device__ __forceinline__ float bf2f_lo(unsigned x) {
  return __builtin_bit_cast(float, x << 16);
}
static __device__ __forceinline__ float bf2f_hi(unsigned x) {
  return __builtin_bit_cast(float, x & 0xffff0000u);
}

// 16-load W burst (4 tiles of 16 cols): 256 B/lane in flight.
#define W_BURST16(W, q0, q1, q2, q3)                                     \
  asm volatile(                                                          \
      "global_load_dwordx4 %[w0], %[a0], off\n\t"                        \
      "global_load_dwordx4 %[w1], %[a0], off offset:16\n\t"              \
      "global_load_dwordx4 %[w2], %[a0], off offset:128\n\t"             \
      "global_load_dwordx4 %[w3], %[a0], off offset:144\n\t"             \
      "global_load_dwordx4 %[w4], %[a1], off\n\t"                        \
      "global_load_dwordx4 %[w5], %[a1], off offset:16\n\t"              \
      "global_load_dwordx4 %[w6], %[a1], off offset:128\n\t"             \
      "global_load_dwordx4 %[w7], %[a1], off offset:144\n\t"             \
      "global_load_dwordx4 %[w8], %[a2], off\n\t"                        \
      "global_load_dwordx4 %[w9], %[a2], off offset:16\n\t"              \
      "global_load_dwordx4 %[w10], %[a2], off offset:128\n\t"            \
      "global_load_dwordx4 %[w11], %[a2], off offset:144\n\t"            \
      "global_load_dwordx4 %[w12], %[a3], off\n\t"                       \
      "global_load_dwordx4 %[w13], %[a3], off offset:16\n\t"             \
      "global_load_dwordx4 %[w14], %[a3], off offset:128\n\t"            \
      "global_load_dwordx4 %[w15], %[a3], off offset:144\n\t"            \
      : [w0] "=&v"(W[0]), [w1] "=&v"(W[1]), [w2] "=&v"(W[2]),            \
        [w3] "=&v"(W[3]), [w4] "=&v"(W[4]), [w5] "=&v"(W[5]),            \
        [w6] "=&v"(W[6]), [w7] "=&v"(W[7]), [w8] "=&v"(W[8]),            \
        [w9] "=&v"(W[9]), [w10] "=&v"(W[10]), [w11] "=&v"(W[11]),        \
        [w12] "=&v"(W[12]), [w13] "=&v"(W[13]), [w14] "=&v"(W[14]),      \
        [w15] "=&v"(W[15])                                               \
      : [a0] "v"(q0), [a1] "v"(q1), [a2] "v"(q2), [a3] "v"(q3)           \
      : "memory")

#define VM_WAIT16                                       \
  do {                                                  \
    asm volatile("s_waitcnt vmcnt(16)" ::: "memory");   \
    __builtin_amdgcn_sched_barrier(0);                  \
  } while (0)
#define VM_WAIT8                                        \
  do {                                                  \
    asm volatile("s_waitcnt vmcnt(8)" ::: "memory");    \
    __builtin_amdgcn_sched_barrier(0);                  \
  } while (0)

// One 16-col tile: pack W->bf16, 8 MFMA (4 b-tiles x K64), emit 8 packed
// uint (2 per bt) for the permuted store layout.
#define TILE(W, TL, C, O0, O1, O2, O3, O4, O5, O6, O7)                        \
  do {                                                                        \
    const f32x4 A0 = (W)[(TL) * 4 + 0];                                       \
    const f32x4 A1 = (W)[(TL) * 4 + 1];                                       \
    const f32x4 A2 = (W)[(TL) * 4 + 2];                                       \
    const f32x4 A3 = (W)[(TL) * 4 + 3];                                       \
    short8 wf0, wf1;                                                          \
    wf0[0] = (short)f2bf(A0[0]); wf0[1] = (short)f2bf(A0[1]);                 \
    wf0[2] = (short)f2bf(A0[2]); wf0[3] = (short)f2bf(A0[3]);                 \
    wf0[4] = (short)f2bf(A1[0]); wf0[5] = (short)f2bf(A1[1]);                 \
    wf0[6] = (short)f2bf(A1[2]); wf0[7] = (short)f2bf(A1[3]);                 \
    wf1[0] = (short)f2bf(A2[0]); wf1[1] = (short)f2bf(A2[1]);                 \
    wf1[2] = (short)f2bf(A2[2]); wf1[3] = (short)f2bf(A2[3]);                 \
    wf1[4] = (short)f2bf(A3[0]); wf1[5] = (short)f2bf(A3[1]);                 \
    wf1[6] = (short)f2bf(A3[2]); wf1[7] = (short)f2bf(A3[3]);                 \
    float4 bf = *(const float4*)&bias_lds[wave * 256 + (C) * 64 + (TL) * 16 + \
                                          quad * 4];                          \
    f32x4 a0 = (f32x4){0.f, 0.f, 0.f, 0.f};                                   \
    f32x4 a1 = a0, a2 = a0, a3 = a0;                                          \
    a0 = __builtin_amdgcn_mfma_f32_16x16x32_bf16(wf0, uf[0][0], a0, 0, 0, 0); \
    a0 = __builtin_amdgcn_mfma_f32_16x16x32_bf16(wf1, uf[0][1], a0, 0, 0, 0); \
    a1 = __builtin_amdgcn_mfma_f32_16x16x32_bf16(wf0, uf[1][0], a1, 0, 0, 0); \
    a1 = __builtin_amdgcn_mfma_f32_16x16x32_bf16(wf1, uf[1][1], a1, 0, 0, 0); \
    a2 = __builtin_amdgcn_mfma_f32_16x16x32_bf16(wf0, uf[2][0], a2, 0, 0, 0); \
    a2 = __builtin_amdgcn_mfma_f32_16x16x32_bf16(wf1, uf[2][1], a2, 0, 0, 0); \
    a3 = __builtin_amdgcn_mfma_f32_16x16x32_bf16(wf0, uf[3][0], a3, 0, 0, 0); \
    a3 = __builtin_amdgcn_mfma_f32_16x16x32_bf16(wf1, uf[3][1], a3, 0, 0, 0); \
    O0 = f2bf(a0[0] + bf.x) | ((unsigned)f2bf(a0[1] + bf.y) << 16);           \
    O1 = f2bf(a0[2] + bf.z) | ((unsigned)f2bf(a0[3] + bf.w) << 16);           \
    O2 = f2bf(a1[0] + bf.x) | ((unsigned)f2bf(a1[1] + bf.y) << 16);           \
    O3 = f2bf(a1[2] + bf.z) | ((unsigned)f2bf(a1[3] + bf.w) << 16);           \
    O4 = f2bf(a2[0] + bf.x) | ((unsigned)f2bf(a2[1] + bf.y) << 16);           \
    O5 = f2bf(a2[2] + bf.z) | ((unsigned)f2bf(a2[3] + bf.w) << 16);           \
    O6 = f2bf(a3[0] + bf.x) | ((unsigned)f2bf(a3[1] + bf.y) << 16);           \
    O7 = f2bf(a3[2] + bf.z) | ((unsigned)f2bf(a3[3] + bf.w) << 16);           \
  } while (0)

// One chunk (4 tiles = 64 cols): per bt one 32B run per lane, stored as
// 2x global_store_dwordx4 (pairs complete full 128B lines) into the
// block-local [n][b][f'] window.
#define STEP(W, C)                                                            \
  do {                                                                        \
    u32x4 kA0, kA1, kA2, kA3, kB0, kB1, kB2, kB3;                             \
    TILE(W, 0, C, kA0.x, kA0.y, kA1.x, kA1.y, kA2.x, kA2.y, kA3.x, kA3.y);    \
    TILE(W, 1, C, kA0.z, kA0.w, kA1.z, kA1.w, kA2.z, kA2.w, kA3.z, kA3.w);    \
    TILE(W, 2, C, kB0.x, kB0.y, kB1.x, kB1.y, kB2.x, kB2.y, kB3.x, kB3.y);    \
    TILE(W, 3, C, kB0.z, kB0.w, kB1.z, kB1.w, kB2.z, kB2.w, kB3.z, kB3.w);    \
    const unsigned short* c0 = sb0 + (C) * 64;                                \
    const unsigned short* c1 = sb1 + (C) * 64;                                \
    const unsigned short* c2 = sb2 + (C) * 64;                                \
    const unsigned short* c3 = sb3 + (C) * 64;                                \
    asm volatile(                                                             \
        "global_store_dwordx4 %[a0], %[d0], off\n\t"                          \
        "global_store_dwordx4 %[a0], %[d1], off offset:16\n\t"                \
        "global_store_dwordx4 %[a1], %[d2], off\n\t"                          \
        "global_store_dwordx4 %[a1], %[d3], off offset:16\n\t"                \
        "global_store_dwordx4 %[a2], %[d4], off\n\t"                          \
        "global_store_dwordx4 %[a2], %[d5], off offset:16\n\t"                \
        "global_store_dwordx4 %[a3], %[d6], off\n\t"                          \
        "global_store_dwordx4 %[a3], %[d7], off offset:16\n\t"                \
        :: [a0] "v"(c0), [a1] "v"(c1), [a2] "v"(c2), [a3] "v"(c3),            \
           [d0] "v"(kA0), [d1] "v"(kB0), [d2] "v"(kA1), [d3] "v"(kB1),        \
           [d4] "v"(kA2), [d5] "v"(kB2), [d6] "v"(kA3), [d7] "v"(kB3)         \
        : "memory");                                                          \
  } while (0)

// K1: u_hat stored [n][b][f'] (f' permuted within 64-col blocks:
// f' = quad*16 + tile*4 + j), bf16. Grid (n, half). Wave owns 256 cols =
// 4 chunks of 64. 16-load asm bursts double-buffered, counted vmcnt,
// pre-barrier prologue bursts, block-contiguous store region.
// (Byte-identical to the round-12 version that passed at 433us.)
__global__ __launch_bounds__(256, 2) void k_gemm(
    const float* __restrict__ u, const float* __restrict__ w,
    const float* __restrict__ bias, unsigned short* __restrict__ uhat,
    float* __restrict__ szero) {
  const int n = blockIdx.x;
  const int half = blockIdx.y;
  __shared__ __align__(16) unsigned short a_lds[64 * 72];
  __shared__ __align__(16) float bias_lds[1024];
  const int t = threadIdx.x;
  const int lane = t & 63;
  const int wave = t >> 6;
  const int row16 = lane & 15;
  const int quad = lane >> 4;

  // zero s1/s2/s3 (3*131072 floats over 2048 blocks x 192)
  {
    const int bid = half * 1024 + n;
    if (t < 192) szero[bid * 192 + t] = 0.f;
  }

  // ---- stage u[:,n,:] (bf16) + bias into LDS (all compiler VMEM here)
  {
    const int b = t >> 2;
    const int i0 = (t & 3) * 16;
    const float* src = u + (size_t)b * (NIN * IVL) + (size_t)n * IVL + i0;
    unsigned short* dst = a_lds + b * 72 + i0;
#pragma unroll
    for (int q = 0; q < 4; ++q) {
      float4 v = *(const float4*)(src + q * 4);
      dst[q * 4 + 0] = f2bf(v.x);
      dst[q * 4 + 1] = f2bf(v.y);
      dst[q * 4 + 2] = f2bf(v.z);
      dst[q * 4 + 3] = f2bf(v.w);
    }
    *(float4*)&bias_lds[t * 4] =
        *(const float4*)(bias + (size_t)n * OLSZ + half * 1024 + t * 4);
  }

  // ---- prologue bursts (chunks 0,1) BEFORE the barrier
  const float* wp = w + (size_t)n * (OLSZ * IVL) +
                    (size_t)(half * 1024 + wave * 256 + row16) * IVL + quad * 8;
  f32x4 bufA[16], bufB[16];
  W_BURST16(bufA, wp, wp + 1024, wp + 2048, wp + 3072);
  W_BURST16(bufB, wp + 4096, wp + 5120, wp + 6144, wp + 7168);

  // manual barrier: LDS-only wait, vmcnt untouched (bursts stay in flight)
  asm volatile("s_waitcnt lgkmcnt(0)" ::: "memory");
  __builtin_amdgcn_s_barrier();

  // ---- u fragments, read once, kept in registers
  short8 uf[4][2];
#pragma unroll
  for (int bt = 0; bt < 4; ++bt) {
#pragma unroll
    for (int ks = 0; ks < 2; ++ks) {
      uf[bt][ks] =
          *(const short8*)(a_lds + (bt * 16 + row16) * 72 + ks * 32 + quad * 8);
    }
  }

  // [n][b][f'] store bases: b = bt*16 + row16 -> rows 4KB apart
  const unsigned short* sb0 = uhat + ((size_t)n * 64 + row16) * OLSZ +
                              half * 1024 + wave * 256 + quad * 16;
  const unsigned short* sb1 = sb0 + (size_t)16 * OLSZ;
  const unsigned short* sb2 = sb0 + (size_t)32 * OLSZ;
  const unsigned short* sb3 = sb0 + (size_t)48 * OLSZ;

  // ---- 4-chunk pipelined loop
  VM_WAIT16; STEP(bufA, 0); W_BURST16(bufA, wp + 8192, wp + 9216, wp + 10240, wp + 11264);
  VM_WAIT16; STEP(bufB, 1); W_BURST16(bufB, wp + 12288, wp + 13312, wp + 14336, wp + 15360);
  VM_WAIT16; STEP(bufA, 2);
  VM_WAIT8;  STEP(bufB, 3);
}

// K2: s1[b,f'] = sum_n uhat[n][b][f']. Block (b, n-chunk of 128): reads the
// full 4KB row per n, register accumulate, 8 atomics.
__global__ __launch_bounds__(256) void k_sum_n(
    const unsigned short* __restrict__ uhat, float* __restrict__ s1) {
  const int b = blockIdx.x >> 3;
  const int nc = blockIdx.x & 7;  // 8 chunks of 128 n
  const int t = threadIdx.x;
  const unsigned short* base =
      uhat + ((size_t)(nc * 128) * 64 + b) * OLSZ + t * 8;
  float acc[8];
#pragma unroll
  for (int j = 0; j < 8; ++j) acc[j] = 0.f;
#pragma unroll 4
  for (int k = 0; k < 128; ++k) {
    uint4 p = *(const uint4*)(base + (size_t)k * 64 * OLSZ);
    unsigned xs[4] = {p.x, p.y, p.z, p.w};
#pragma unroll
    for (int h = 0; h < 4; ++h) {
      acc[2 * h] += bf2f_lo(xs[h]);
      acc[2 * h + 1] += bf2f_hi(xs[h]);
    }
  }
  float* s = s1 + (size_t)b * OLSZ + t * 8;
#pragma unroll
  for (int j = 0; j < 8; ++j) atomicAdd(s + j, acc[j]);
}

// K3/K4: one routing iteration on the permuted [n][b][f'] layout, b1-free.
// launch_bounds(256,4) caps VGPR at 128 (stay under the occupancy cliff);
// bf16 unpack is done on the fly twice instead of holding ud[32] live.
__global__ __launch_bounds__(256, 4) void k_route(
    const unsigned short* __restrict__ uhat, const float* __restrict__ svA,
    float scaleA, const float* __restrict__ svB, float scaleB, int useB,
    float* __restrict__ sout) {
  const int b = blockIdx.x >> 5;
  const int chunk = blockIdx.x & 31;
  const int t = threadIdx.x;
  const int lane = t & 63;
  const int wave = t >> 6;
  __shared__ float red[4][OLSZ];  // 32 KB

  float v[4][8];
#pragma unroll
  for (int q = 0; q < 4; ++q) {
    const float* svp = svA + (size_t)b * OLSZ + q * 512 + lane * 8;
    float4 a0 = *(const float4*)svp;
    float4 a1 = *(const float4*)(svp + 4);
    v[q][0] = a0.x * scaleA; v[q][1] = a0.y * scaleA;
    v[q][2] = a0.z * scaleA; v[q][3] = a0.w * scaleA;
    v[q][4] = a1.x * scaleA; v[q][5] = a1.y * scaleA;
    v[q][6] = a1.z * scaleA; v[q][7] = a1.w * scaleA;
    float p = 0.f;
#pragma unroll
    for (int j = 0; j < 8; ++j) p = fmaf(v[q][j], v[q][j], p);
    p += __shfl_xor(p, 2);
    p += __shfl_xor(p, 4);
    float f = p / ((1.f + p) * (sqrtf(p) + 1e-5f));
#pragma unroll
    for (int j = 0; j < 8; ++j) v[q][j] *= f;
  }
  if (useB) {
#pragma unroll
    for (int q = 0; q < 4; ++q) {
      const float* svp = svB + (size_t)b * OLSZ + q * 512 + lane * 8;
      float4 a0 = *(const float4*)svp;
      float4 a1 = *(const float4*)(svp + 4);
      float w2[8];
      w2[0] = a0.x * scaleB; w2[1] = a0.y * scaleB;
      w2[2] = a0.z * scaleB; w2[3] = a0.w * scaleB;
      w2[4] = a1.x * scaleB; w2[5] = a1.y * scaleB;
      w2[6] = a1.z * scaleB; w2[7] = a1.w * scaleB;
      float p = 0.f;
#pragma unroll
      for (int j = 0; j < 8; ++j) p = fmaf(w2[j], w2[j], p);
      p += __shfl_xor(p, 2);
      p += __shfl_xor(p, 4);
      float f = p / ((1.f + p) * (sqrtf(p) + 1e-5f));
#pragma unroll
      for (int j = 0; j < 8; ++j) v[q][j] = fmaf(w2[j], f, v[q][j]);
    }
  }

  float racc[4][8];
#pragma unroll
  for (int q = 0; q < 4; ++q)
#pragma unroll
    for (int j = 0; j < 8; ++j) racc[q][j] = 0.f;

  const int n0 = chunk * 32 + wave * 8;
  const unsigned short* ub = uhat + ((size_t)n0 * 64 + b) * OLSZ + lane * 8;
  const size_t NSTRIDE = (size_t)64 * OLSZ;  // one n step in [n][b][f']

  uint4 pA[4], pB[4];
#pragma unroll
  for (int q = 0; q < 4; ++q) pA[q] = *(const uint4*)(ub + q * 512);

  auto process = [&](const uint4(&pk)[4]) {
    float d[4];
#pragma unroll
    for (int q = 0; q < 4; ++q) {
      unsigned xs[4] = {pk[q].x, pk[q].y, pk[q].z, pk[q].w};
      float p = 0.f;
#pragma unroll
      for (int h = 0; h < 4; ++h) {
        p = fmaf(bf2f_lo(xs[h]), v[q][2 * h], p);
        p = fmaf(bf2f_hi(xs[h]), v[q][2 * h + 1], p);
      }
      p += __shfl_xor(p, 2);  // reduce over same-o lane group
      p += __shfl_xor(p, 4);
      d[q] = p;
    }
    // softmax over all 64 o: xor levels 1,8,16,32 cover each o once.
    float m = fmaxf(fmaxf(d[0], d[1]), fmaxf(d[2], d[3]));
    m = fmaxf(m, __shfl_xor(m, 1));
    m = fmaxf(m, __shfl_xor(m, 8));
    m = fmaxf(m, __shfl_xor(m, 16));
    m = fmaxf(m, __shfl_xor(m, 32));
    float e0 = __expf(d[0] - m);
    float e1 = __expf(d[1] - m);
    float e2 = __expf(d[2] - m);
    float e3 = __expf(d[3] - m);
    float ls = (e0 + e1) + (e2 + e3);
    ls += __shfl_xor(ls, 1);
    ls += __shfl_xor(ls, 8);
    ls += __shfl_xor(ls, 16);
    ls += __shfl_xor(ls, 32);
    float inv = 1.0f / ls;
    float c[4] = {e0 * inv, e1 * inv, e2 * inv, e3 * inv};
#pragma unroll
    for (int q = 0; q < 4; ++q) {
      unsigned xs[4] = {pk[q].x, pk[q].y, pk[q].z, pk[q].w};
#pragma unroll
      for (int h = 0; h < 4; ++h) {
        racc[q][2 * h] = fmaf(c[q], bf2f_lo(xs[h]), racc[q][2 * h]);
        racc[q][2 * h + 1] = fmaf(c[q], bf2f_hi(xs[h]), racc[q][2 * h + 1]);
      }
    }
  };

#pragma unroll
  for (int kk = 0; kk < 4; ++kk) {
    {
#pragma unroll
      for (int q = 0; q < 4; ++q)
        pB[q] = *(const uint4*)(ub + (size_t)(2 * kk + 1) * NSTRIDE + q * 512);
    }
    process(pA);
    if (2 * kk + 2 < 8) {
#pragma unroll
      for (int q = 0; q < 4; ++q)
        pA[q] = *(const uint4*)(ub + (size_t)(2 * kk + 2) * NSTRIDE + q * 512);
    }
    process(pB);
  }

#pragma unroll
  for (int q = 0; q < 4; ++q) {
    float* dst = &red[wave][q * 512 + lane * 8];
    *(float4*)(dst) =
        make_float4(racc[q][0], racc[q][1], racc[q][2], racc[q][3]);
    *(float4*)(dst + 4) =
        make_float4(racc[q][4], racc[q][5], racc[q][6], racc[q][7]);
  }
  __syncthreads();
  float* so = sout + (size_t)b * OLSZ;
#pragma unroll
  for (int j = 0; j < 8; ++j) {
    const int idx = t + 256 * j;
    float s = (red[0][idx] + red[1][idx]) + (red[2][idx] + red[3][idx]);
    atomicAdd(so + idx, s);
  }
}

// K5: out = squash(s3). s3 is permuted; out must be original layout.
__global__ __launch_bounds__(256) void k_final(const float* __restrict__ s3,
                                               float* __restrict__ out) {
  const int b = blockIdx.x;
  const int t = threadIdx.x;
  __shared__ float norm2[64];
  if (t < 64) norm2[t] = 0.f;
  __syncthreads();
  float scv[8];
#pragma unroll
  for (int k = 0; k < 8; ++k) {
    int idx = t + k * 256;
    float sc = s3[b * OLSZ + idx];
    scv[k] = sc;
    int o = ((idx >> 9) << 4) + (((idx >> 6) & 7) << 1) + ((idx >> 3) & 1);
    atomicAdd(&norm2[o], sc * sc);
  }
  __syncthreads();
#pragma unroll
  for (int k = 0; k < 8; ++k) {
    int idx = t + k * 256;
    int o = ((idx >> 9) << 4) + (((idx >> 6) & 7) << 1) + ((idx >> 3) & 1);
    float n2 = norm2[o];
    float f = n2 / ((1.f + n2) * (sqrtf(n2) + 1e-5f));
    int q2 = (idx >> 4) & 3;  // quad within 64-block
    int t2 = (idx >> 2) & 3;  // tile within 64-block
    int j = idx & 3;
    int fr = (idx & ~63) | (t2 << 4) | (q2 << 2) | j;  // un-permute
    out[b * OLSZ + fr] = scv[k] * f;
  }
}

extern "C" void kernel_launch(void* const* d_in, const int* in_sizes, int n_in,
                              void* d_out, int out_size, void* d_ws,
                              size_t ws_size, hipStream_t stream) {
  const float* u = (const float*)d_in[0];
  const float* w = (const float*)d_in[1];
  const float* bias = (const float*)d_in[2];
  float* out = (float*)d_out;

  char* ws = (char*)d_ws;
  unsigned short* uhat = (unsigned short*)ws;                 // 268435456 B
  float* s1 = (float*)(ws + (size_t)268435456);               // 524288 B
  float* s2 = s1 + 131072;                                    // 524288 B
  float* s3 = s2 + 131072;                                    // 524288 B

  // s1/s2/s3 zeroed inside k_gemm (no hipMemsetAsync in the hot path)
  k_gemm<<<dim3(1024, 2), dim3(256), 0, stream>>>(u, w, bias, uhat, s1);
  k_sum_n<<<dim3(512), dim3(256), 0, stream>>>(uhat, s1);
  // iter 1: v1 = squash(s1/64)
  k_route<<<dim3(2048), dim3(256), 0, stream>>>(uhat, s1, 1.0f / 64.0f,
                                                (const float*)nullptr, 0.f, 0, s2);
  // iter 2: bno = dot(ud, v1 + v2), v2 = squash(s2)
  k_route<<<dim3(2048), dim3(256), 0, stream>>>(uhat, s1, 1.0f / 64.0f,
                                                s2, 1.0f, 1, s3);
  k_final<<<dim3(64), dim3(256), 0, stream>>>(s3, out);
}

// Round 16
// 434.461 us; speedup vs baseline: 2.1699x; 2.1699x over previous
//
#include <hip/hip_runtime.h>

#define NIN 1024
#define IVL 64
#define ONUM 64
#define LVL 32
#define OLSZ 2048  // ONUM*LVL

typedef __attribute__((ext_vector_type(4))) float f32x4;
typedef __attribute__((ext_vector_type(4))) unsigned u32x4;
typedef __attribute__((ext_vector_type(8))) short short8;

static __device__ __forceinline__ unsigned short f2bf(float f) {
  unsigned u = __builtin_bit_cast(unsigned, f);
  u += 0x7fffu + ((u >> 16) & 1u);
  return (unsigned short)(u >> 16);
}
static __device__ __forceinline__ float bf2f_lo(unsigned x) {
  return __builtin_bit_cast(float, x << 16);
}
static __device__ __forceinline__ float bf2f_hi(unsigned x) {
  return __builtin_bit_cast(float, x & 0xffff0000u);
}

// 16-load W burst (4 tiles of 16 cols): 256 B/lane in flight.
#define W_BURST16(W, q0, q1, q2, q3)                                     \
  asm volatile(                                                          \
      "global_load_dwordx4 %[w0], %[a0], off\n\t"                        \
      "global_load_dwordx4 %[w1], %[a0], off offset:16\n\t"              \
      "global_load_dwordx4 %[w2], %[a0], off offset:128\n\t"             \
      "global_load_dwordx4 %[w3], %[a0], off offset:144\n\t"             \
      "global_load_dwordx4 %[w4], %[a1], off\n\t"                        \
      "global_load_dwordx4 %[w5], %[a1], off offset:16\n\t"              \
      "global_load_dwordx4 %[w6], %[a1], off offset:128\n\t"             \
      "global_load_dwordx4 %[w7], %[a1], off offset:144\n\t"             \
      "global_load_dwordx4 %[w8], %[a2], off\n\t"                        \
      "global_load_dwordx4 %[w9], %[a2], off offset:16\n\t"              \
      "global_load_dwordx4 %[w10], %[a2], off offset:128\n\t"            \
      "global_load_dwordx4 %[w11], %[a2], off offset:144\n\t"            \
      "global_load_dwordx4 %[w12], %[a3], off\n\t"                       \
      "global_load_dwordx4 %[w13], %[a3], off offset:16\n\t"             \
      "global_load_dwordx4 %[w14], %[a3], off offset:128\n\t"            \
      "global_load_dwordx4 %[w15], %[a3], off offset:144\n\t"            \
      : [w0] "=&v"(W[0]), [w1] "=&v"(W[1]), [w2] "=&v"(W[2]),            \
        [w3] "=&v"(W[3]), [w4] "=&v"(W[4]), [w5] "=&v"(W[5]),            \
        [w6] "=&v"(W[6]), [w7] "=&v"(W[7]), [w8] "=&v"(W[8]),            \
        [w9] "=&v"(W[9]), [w10] "=&v"(W[10]), [w11] "=&v"(W[11]),        \
        [w12] "=&v"(W[12]), [w13] "=&v"(W[13]), [w14] "=&v"(W[14]),      \
        [w15] "=&v"(W[15])                                               \
      : [a0] "v"(q0), [a1] "v"(q1), [a2] "v"(q2), [a3] "v"(q3)           \
      : "memory")

#define VM_WAIT16                                       \
  do {                                                  \
    asm volatile("s_waitcnt vmcnt(16)" ::: "memory");   \
    __builtin_amdgcn_sched_barrier(0);                  \
  } while (0)
#define VM_WAIT8                                        \
  do {                                                  \
    asm volatile("s_waitcnt vmcnt(8)" ::: "memory");    \
    __builtin_amdgcn_sched_barrier(0);                  \
  } while (0)

// One 16-col tile: pack W->bf16, 8 MFMA (4 b-tiles x K64), emit 8 packed
// uint (2 per bt) for the permuted store layout.
#define TILE(W, TL, C, O0, O1, O2, O3, O4, O5, O6, O7)                        \
  do {                                                                        \
    const f32x4 A0 = (W)[(TL) * 4 + 0];                                       \
    const f32x4 A1 = (W)[(TL) * 4 + 1];                                       \
    const f32x4 A2 = (W)[(TL) * 4 + 2];                                       \
    const f32x4 A3 = (W)[(TL) * 4 + 3];                                       \
    short8 wf0, wf1;                                                          \
    wf0[0] = (short)f2bf(A0[0]); wf0[1] = (short)f2bf(A0[1]);                 \
    wf0[2] = (short)f2bf(A0[2]); wf0[3] = (short)f2bf(A0[3]);                 \
    wf0[4] = (short)f2bf(A1[0]); wf0[5] = (short)f2bf(A1[1]);                 \
    wf0[6] = (short)f2bf(A1[2]); wf0[7] = (short)f2bf(A1[3]);                 \
    wf1[0] = (short)f2bf(A2[0]); wf1[1] = (short)f2bf(A2[1]);                 \
    wf1[2] = (short)f2bf(A2[2]); wf1[3] = (short)f2bf(A2[3]);                 \
    wf1[4] = (short)f2bf(A3[0]); wf1[5] = (short)f2bf(A3[1]);                 \
    wf1[6] = (short)f2bf(A3[2]); wf1[7] = (short)f2bf(A3[3]);                 \
    float4 bf = *(const float4*)&bias_lds[wave * 256 + (C) * 64 + (TL) * 16 + \
                                          quad * 4];                          \
    f32x4 a0 = (f32x4){0.f, 0.f, 0.f, 0.f};                                   \
    f32x4 a1 = a0, a2 = a0, a3 = a0;                                          \
    a0 = __builtin_amdgcn_mfma_f32_16x16x32_bf16(wf0, uf[0][0], a0, 0, 0, 0); \
    a0 = __builtin_amdgcn_mfma_f32_16x16x32_bf16(wf1, uf[0][1], a0, 0, 0, 0); \
    a1 = __builtin_amdgcn_mfma_f32_16x16x32_bf16(wf0, uf[1][0], a1, 0, 0, 0); \
    a1 = __builtin_amdgcn_mfma_f32_16x16x32_bf16(wf1, uf[1][1], a1, 0, 0, 0); \
    a2 = __builtin_amdgcn_mfma_f32_16x16x32_bf16(wf0, uf[2][0], a2, 0, 0, 0); \
    a2 = __builtin_amdgcn_mfma_f32_16x16x32_bf16(wf1, uf[2][1], a2, 0, 0, 0); \
    a3 = __builtin_amdgcn_mfma_f32_16x16x32_bf16(wf0, uf[3][0], a3, 0, 0, 0); \
    a3 = __builtin_amdgcn_mfma_f32_16x16x32_bf16(wf1, uf[3][1], a3, 0, 0, 0); \
    O0 = f2bf(a0[0] + bf.x) | ((unsigned)f2bf(a0[1] + bf.y) << 16);           \
    O1 = f2bf(a0[2] + bf.z) | ((unsigned)f2bf(a0[3] + bf.w) << 16);           \
    O2 = f2bf(a1[0] + bf.x) | ((unsigned)f2bf(a1[1] + bf.y) << 16);           \
    O3 = f2bf(a1[2] + bf.z) | ((unsigned)f2bf(a1[3] + bf.w) << 16);           \
    O4 = f2bf(a2[0] + bf.x) | ((unsigned)f2bf(a2[1] + bf.y) << 16);           \
    O5 = f2bf(a2[2] + bf.z) | ((unsigned)f2bf(a2[3] + bf.w) << 16);           \
    O6 = f2bf(a3[0] + bf.x) | ((unsigned)f2bf(a3[1] + bf.y) << 16);           \
    O7 = f2bf(a3[2] + bf.z) | ((unsigned)f2bf(a3[3] + bf.w) << 16);           \
  } while (0)

// One chunk (4 tiles = 64 cols): per bt one 32B run per lane, stored as
// 2x global_store_dwordx4 (pairs complete full 128B lines) into the
// block-local [n][b][f'] window.
#define STEP(W, C)                                                            \
  do {                                                                        \
    u32x4 kA0, kA1, kA2, kA3, kB0, kB1, kB2, kB3;                             \
    TILE(W, 0, C, kA0.x, kA0.y, kA1.x, kA1.y, kA2.x, kA2.y, kA3.x, kA3.y);    \
    TILE(W, 1, C, kA0.z, kA0.w, kA1.z, kA1.w, kA2.z, kA2.w, kA3.z, kA3.w);    \
    TILE(W, 2, C, kB0.x, kB0.y, kB1.x, kB1.y, kB2.x, kB2.y, kB3.x, kB3.y);    \
    TILE(W, 3, C, kB0.z, kB0.w, kB1.z, kB1.w, kB2.z, kB2.w, kB3.z, kB3.w);    \
    const unsigned short* c0 = sb0 + (C) * 64;                                \
    const unsigned short* c1 = sb1 + (C) * 64;                                \
    const unsigned short* c2 = sb2 + (C) * 64;                                \
    const unsigned short* c3 = sb3 + (C) * 64;                                \
    asm volatile(                                                             \
        "global_store_dwordx4 %[a0], %[d0], off\n\t"                          \
        "global_store_dwordx4 %[a0], %[d1], off offset:16\n\t"                \
        "global_store_dwordx4 %[a1], %[d2], off\n\t"                          \
        "global_store_dwordx4 %[a1], %[d3], off offset:16\n\t"                \
        "global_store_dwordx4 %[a2], %[d4], off\n\t"                          \
        "global_store_dwordx4 %[a2], %[d5], off offset:16\n\t"                \
        "global_store_dwordx4 %[a3], %[d6], off\n\t"                          \
        "global_store_dwordx4 %[a3], %[d7], off offset:16\n\t"                \
        :: [a0] "v"(c0), [a1] "v"(c1), [a2] "v"(c2), [a3] "v"(c3),            \
           [d0] "v"(kA0), [d1] "v"(kB0), [d2] "v"(kA1), [d3] "v"(kB1),        \
           [d4] "v"(kA2), [d5] "v"(kB2), [d6] "v"(kA3), [d7] "v"(kB3)         \
        : "memory");                                                          \
  } while (0)

// K1: u_hat stored [n][b][f'] (f' permuted within 64-col blocks:
// f' = quad*16 + tile*4 + j), bf16. Grid (n, half). Wave owns 256 cols =
// 4 chunks of 64. 16-load asm bursts double-buffered, counted vmcnt,
// pre-barrier prologue bursts, block-contiguous store region.
// (Byte-identical to the round-12 version that passed at 433us. The vmcnt(16)
// discipline drains prior stores before any transient-reg reuse -- proven
// safe; restructures of this loop NaN'd twice, do not touch.)
__global__ __launch_bounds__(256, 2) void k_gemm(
    const float* __restrict__ u, const float* __restrict__ w,
    const float* __restrict__ bias, unsigned short* __restrict__ uhat,
    float* __restrict__ szero) {
  const int n = blockIdx.x;
  const int half = blockIdx.y;
  __shared__ __align__(16) unsigned short a_lds[64 * 72];
  __shared__ __align__(16) float bias_lds[1024];
  const int t = threadIdx.x;
  const int lane = t & 63;
  const int wave = t >> 6;
  const int row16 = lane & 15;
  const int quad = lane >> 4;

  // zero s1/s2/s3 (3*131072 floats over 2048 blocks x 192)
  {
    const int bid = half * 1024 + n;
    if (t < 192) szero[bid * 192 + t] = 0.f;
  }

  // ---- stage u[:,n,:] (bf16) + bias into LDS (all compiler VMEM here)
  {
    const int b = t >> 2;
    const int i0 = (t & 3) * 16;
    const float* src = u + (size_t)b * (NIN * IVL) + (size_t)n * IVL + i0;
    unsigned short* dst = a_lds + b * 72 + i0;
#pragma unroll
    for (int q = 0; q < 4; ++q) {
      float4 v = *(const float4*)(src + q * 4);
      dst[q * 4 + 0] = f2bf(v.x);
      dst[q * 4 + 1] = f2bf(v.y);
      dst[q * 4 + 2] = f2bf(v.z);
      dst[q * 4 + 3] = f2bf(v.w);
    }
    *(float4*)&bias_lds[t * 4] =
        *(const float4*)(bias + (size_t)n * OLSZ + half * 1024 + t * 4);
  }

  // ---- prologue bursts (chunks 0,1) BEFORE the barrier
  const float* wp = w + (size_t)n * (OLSZ * IVL) +
                    (size_t)(half * 1024 + wave * 256 + row16) * IVL + quad * 8;
  f32x4 bufA[16], bufB[16];
  W_BURST16(bufA, wp, wp + 1024, wp + 2048, wp + 3072);
  W_BURST16(bufB, wp + 4096, wp + 5120, wp + 6144, wp + 7168);

  // manual barrier: LDS-only wait, vmcnt untouched (bursts stay in flight)
  asm volatile("s_waitcnt lgkmcnt(0)" ::: "memory");
  __builtin_amdgcn_s_barrier();

  // ---- u fragments, read once, kept in registers
  short8 uf[4][2];
#pragma unroll
  for (int bt = 0; bt < 4; ++bt) {
#pragma unroll
    for (int ks = 0; ks < 2; ++ks) {
      uf[bt][ks] =
          *(const short8*)(a_lds + (bt * 16 + row16) * 72 + ks * 32 + quad * 8);
    }
  }

  // [n][b][f'] store bases: b = bt*16 + row16 -> rows 4KB apart
  const unsigned short* sb0 = uhat + ((size_t)n * 64 + row16) * OLSZ +
                              half * 1024 + wave * 256 + quad * 16;
  const unsigned short* sb1 = sb0 + (size_t)16 * OLSZ;
  const unsigned short* sb2 = sb0 + (size_t)32 * OLSZ;
  const unsigned short* sb3 = sb0 + (size_t)48 * OLSZ;

  // ---- 4-chunk pipelined loop
  VM_WAIT16; STEP(bufA, 0); W_BURST16(bufA, wp + 8192, wp + 9216, wp + 10240, wp + 11264);
  VM_WAIT16; STEP(bufB, 1); W_BURST16(bufB, wp + 12288, wp + 13312, wp + 14336, wp + 15360);
  VM_WAIT16; STEP(bufA, 2);
  VM_WAIT8;  STEP(bufB, 3);
}

// K2: s1[b,f'] = sum_n uhat[n][b][f']. Block (b, n-chunk of 128): reads the
// full 4KB row per n, register accumulate, 8 atomics.
__global__ __launch_bounds__(256) void k_sum_n(
    const unsigned short* __restrict__ uhat, float* __restrict__ s1) {
  const int b = blockIdx.x >> 3;
  const int nc = blockIdx.x & 7;  // 8 chunks of 128 n
  const int t = threadIdx.x;
  const unsigned short* base =
      uhat + ((size_t)(nc * 128) * 64 + b) * OLSZ + t * 8;
  float acc[8];
#pragma unroll
  for (int j = 0; j < 8; ++j) acc[j] = 0.f;
#pragma unroll 4
  for (int k = 0; k < 128; ++k) {
    uint4 p = *(const uint4*)(base + (size_t)k * 64 * OLSZ);
    unsigned xs[4] = {p.x, p.y, p.z, p.w};
#pragma unroll
    for (int h = 0; h < 4; ++h) {
      acc[2 * h] += bf2f_lo(xs[h]);
      acc[2 * h + 1] += bf2f_hi(xs[h]);
    }
  }
  float* s = s1 + (size_t)b * OLSZ + t * 8;
#pragma unroll
  for (int j = 0; j < 8; ++j) atomicAdd(s + j, acc[j]);
}

// K3/K4: one routing iteration on the permuted [n][b][f'] layout, b1-free.
// NO launch_bounds min-waves: r15 proved capping below natural VGPR makes
// hipcc rematerialize global loads (FETCH 2x) + spill to scratch (WRITE
// +590MB) -- 344us/dispatch vs ~50us natural. Let the allocator breathe.
__global__ __launch_bounds__(256) void k_route(
    const unsigned short* __restrict__ uhat, const float* __restrict__ svA,
    float scaleA, const float* __restrict__ svB, float scaleB, int useB,
    float* __restrict__ sout) {
  const int b = blockIdx.x >> 5;
  const int chunk = blockIdx.x & 31;
  const int t = threadIdx.x;
  const int lane = t & 63;
  const int wave = t >> 6;
  __shared__ float red[4][OLSZ];  // 32 KB

  float v[4][8];
#pragma unroll
  for (int q = 0; q < 4; ++q) {
    const float* svp = svA + (size_t)b * OLSZ + q * 512 + lane * 8;
    float4 a0 = *(const float4*)svp;
    float4 a1 = *(const float4*)(svp + 4);
    v[q][0] = a0.x * scaleA; v[q][1] = a0.y * scaleA;
    v[q][2] = a0.z * scaleA; v[q][3] = a0.w * scaleA;
    v[q][4] = a1.x * scaleA; v[q][5] = a1.y * scaleA;
    v[q][6] = a1.z * scaleA; v[q][7] = a1.w * scaleA;
    float p = 0.f;
#pragma unroll
    for (int j = 0; j < 8; ++j) p = fmaf(v[q][j], v[q][j], p);
    p += __shfl_xor(p, 2);
    p += __shfl_xor(p, 4);
    float f = p / ((1.f + p) * (sqrtf(p) + 1e-5f));
#pragma unroll
    for (int j = 0; j < 8; ++j) v[q][j] *= f;
  }
  if (useB) {
#pragma unroll
    for (int q = 0; q < 4; ++q) {
      const float* svp = svB + (size_t)b * OLSZ + q * 512 + lane * 8;
      float4 a0 = *(const float4*)svp;
      float4 a1 = *(const float4*)(svp + 4);
      float w2[8];
      w2[0] = a0.x * scaleB; w2[1] = a0.y * scaleB;
      w2[2] = a0.z * scaleB; w2[3] = a0.w * scaleB;
      w2[4] = a1.x * scaleB; w2[5] = a1.y * scaleB;
      w2[6] = a1.z * scaleB; w2[7] = a1.w * scaleB;
      float p = 0.f;
#pragma unroll
      for (int j = 0; j < 8; ++j) p = fmaf(w2[j], w2[j], p);
      p += __shfl_xor(p, 2);
      p += __shfl_xor(p, 4);
      float f = p / ((1.f + p) * (sqrtf(p) + 1e-5f));
#pragma unroll
      for (int j = 0; j < 8; ++j) v[q][j] = fmaf(w2[j], f, v[q][j]);
    }
  }

  float racc[4][8];
#pragma unroll
  for (int q = 0; q < 4; ++q)
#pragma unroll
    for (int j = 0; j < 8; ++j) racc[q][j] = 0.f;

  const int n0 = chunk * 32 + wave * 8;
  const unsigned short* ub = uhat + ((size_t)n0 * 64 + b) * OLSZ + lane * 8;
  const size_t NSTRIDE = (size_t)64 * OLSZ;  // one n step in [n][b][f']

  uint4 pA[4], pB[4];
#pragma unroll
  for (int q = 0; q < 4; ++q) pA[q] = *(const uint4*)(ub + q * 512);

  auto process = [&](const uint4(&pk)[4]) {
    float ud[4][8];
    float d[4];
#pragma unroll
    for (int q = 0; q < 4; ++q) {
      unsigned xs[4] = {pk[q].x, pk[q].y, pk[q].z, pk[q].w};
#pragma unroll
      for (int h = 0; h < 4; ++h) {
        ud[q][2 * h] = bf2f_lo(xs[h]);
        ud[q][2 * h + 1] = bf2f_hi(xs[h]);
      }
      float p = 0.f;
#pragma unroll
      for (int j = 0; j < 8; ++j) p = fmaf(ud[q][j], v[q][j], p);
      p += __shfl_xor(p, 2);  // reduce over same-o lane group
      p += __shfl_xor(p, 4);
      d[q] = p;
    }
    // softmax over all 64 o: xor levels 1,8,16,32 cover each o once.
    float m = fmaxf(fmaxf(d[0], d[1]), fmaxf(d[2], d[3]));
    m = fmaxf(m, __shfl_xor(m, 1));
    m = fmaxf(m, __shfl_xor(m, 8));
    m = fmaxf(m, __shfl_xor(m, 16));
    m = fmaxf(m, __shfl_xor(m, 32));
    float e0 = __expf(d[0] - m);
    float e1 = __expf(d[1] - m);
    float e2 = __expf(d[2] - m);
    float e3 = __expf(d[3] - m);
    float ls = (e0 + e1) + (e2 + e3);
    ls += __shfl_xor(ls, 1);
    ls += __shfl_xor(ls, 8);
    ls += __shfl_xor(ls, 16);
    ls += __shfl_xor(ls, 32);
    float inv = 1.0f / ls;
    float c[4] = {e0 * inv, e1 * inv, e2 * inv, e3 * inv};
#pragma unroll
    for (int q = 0; q < 4; ++q) {
#pragma unroll
      for (int j = 0; j < 8; ++j)
        racc[q][j] = fmaf(c[q], ud[q][j], racc[q][j]);
    }
  };

#pragma unroll
  for (int kk = 0; kk < 4; ++kk) {
    {
#pragma unroll
      for (int q = 0; q < 4; ++q)
        pB[q] = *(const uint4*)(ub + (size_t)(2 * kk + 1) * NSTRIDE + q * 512);
    }
    process(pA);
    if (2 * kk + 2 < 8) {
#pragma unroll
      for (int q = 0; q < 4; ++q)
        pA[q] = *(const uint4*)(ub + (size_t)(2 * kk + 2) * NSTRIDE + q * 512);
    }
    process(pB);
  }

#pragma unroll
  for (int q = 0; q < 4; ++q) {
    float* dst = &red[wave][q * 512 + lane * 8];
    *(float4*)(dst) =
        make_float4(racc[q][0], racc[q][1], racc[q][2], racc[q][3]);
    *(float4*)(dst + 4) =
        make_float4(racc[q][4], racc[q][5], racc[q][6], racc[q][7]);
  }
  __syncthreads();
  float* so = sout + (size_t)b * OLSZ;
#pragma unroll
  for (int j = 0; j < 8; ++j) {
    const int idx = t + 256 * j;
    float s = (red[0][idx] + red[1][idx]) + (red[2][idx] + red[3][idx]);
    atomicAdd(so + idx, s);
  }
}

// K5: out = squash(s3). s3 is permuted; out must be original layout.
__global__ __launch_bounds__(256) void k_final(const float* __restrict__ s3,
                                               float* __restrict__ out) {
  const int b = blockIdx.x;
  const int t = threadIdx.x;
  __shared__ float norm2[64];
  if (t < 64) norm2[t] = 0.f;
  __syncthreads();
  float scv[8];
#pragma unroll
  for (int k = 0; k < 8; ++k) {
    int idx = t + k * 256;
    float sc = s3[b * OLSZ + idx];
    scv[k] = sc;
    int o = ((idx >> 9) << 4) + (((idx >> 6) & 7) << 1) + ((idx >> 3) & 1);
    atomicAdd(&norm2[o], sc * sc);
  }
  __syncthreads();
#pragma unroll
  for (int k = 0; k < 8; ++k) {
    int idx = t + k * 256;
    int o = ((idx >> 9) << 4) + (((idx >> 6) & 7) << 1) + ((idx >> 3) & 1);
    float n2 = norm2[o];
    float f = n2 / ((1.f + n2) * (sqrtf(n2) + 1e-5f));
    int q2 = (idx >> 4) & 3;  // quad within 64-block
    int t2 = (idx >> 2) & 3;  // tile within 64-block
    int j = idx & 3;
    int fr = (idx & ~63) | (t2 << 4) | (q2 << 2) | j;  // un-permute
    out[b * OLSZ + fr] = scv[k] * f;
  }
}

extern "C" void kernel_launch(void* const* d_in, const int* in_sizes, int n_in,
                              void* d_out, int out_size, void* d_ws,
                              size_t ws_size, hipStream_t stream) {
  const float* u = (const float*)d_in[0];
  const float* w = (const float*)d_in[1];
  const float* bias = (const float*)d_in[2];
  float* out = (float*)d_out;

  char* ws = (char*)d_ws;
  unsigned short* uhat = (unsigned short*)ws;                 // 268435456 B
  float* s1 = (float*)(ws + (size_t)268435456);               // 524288 B
  float* s2 = s1 + 131072;                                    // 524288 B
  float* s3 = s2 + 131072;                                    // 524288 B

  // s1/s2/s3 zeroed inside k_gemm (no hipMemsetAsync in the hot path)
  k_gemm<<<dim3(1024, 2), dim3(256), 0, stream>>>(u, w, bias, uhat, s1);
  k_sum_n<<<dim3(512), dim3(256), 0, stream>>>(uhat, s1);
  // iter 1: v1 = squash(s1/64)
  k_route<<<dim3(2048), dim3(256), 0, stream>>>(uhat, s1, 1.0f / 64.0f,
                                                (const float*)nullptr, 0.f, 0, s2);
  // iter 2: bno = dot(ud, v1 + v2), v2 = squash(s2)
  k_route<<<dim3(2048), dim3(256), 0, stream>>>(uhat, s1, 1.0f / 64.0f,
                                                s2, 1.0f, 1, s3);
  k_final<<<dim3(64), dim3(256), 0, stream>>>(s3, out);
}

// Round 17
// 432.584 us; speedup vs baseline: 2.1793x; 1.0043x over previous
//
#include <hip/hip_runtime.h>

#define NIN 1024
#define IVL 64
#define ONUM 64
#define LVL 32
#define OLSZ 2048  // ONUM*LVL

typedef __attribute__((ext_vector_type(4))) float f32x4;
typedef __attribute__((ext_vector_type(4))) unsigned u32x4;
typedef __attribute__((ext_vector_type(8))) short short8;

static __device__ __forceinline__ unsigned short f2bf(float f) {
  unsigned u = __builtin_bit_cast(unsigned, f);
  u += 0x7fffu + ((u >> 16) & 1u);
  return (unsigned short)(u >> 16);
}
static __device__ __forceinline__ float bf2f_lo(unsigned x) {
  return __builtin_bit_cast(float, x << 16);
}
static __device__ __forceinline__ float bf2f_hi(unsigned x) {
  return __builtin_bit_cast(float, x & 0xffff0000u);
}

// 16-load W burst (4 tiles of 16 cols): 256 B/lane in flight.
#define W_BURST16(W, q0, q1, q2, q3)                                     \
  asm volatile(                                                          \
      "global_load_dwordx4 %[w0], %[a0], off\n\t"                        \
      "global_load_dwordx4 %[w1], %[a0], off offset:16\n\t"              \
      "global_load_dwordx4 %[w2], %[a0], off offset:128\n\t"             \
      "global_load_dwordx4 %[w3], %[a0], off offset:144\n\t"             \
      "global_load_dwordx4 %[w4], %[a1], off\n\t"                        \
      "global_load_dwordx4 %[w5], %[a1], off offset:16\n\t"              \
      "global_load_dwordx4 %[w6], %[a1], off offset:128\n\t"             \
      "global_load_dwordx4 %[w7], %[a1], off offset:144\n\t"             \
      "global_load_dwordx4 %[w8], %[a2], off\n\t"                        \
      "global_load_dwordx4 %[w9], %[a2], off offset:16\n\t"              \
      "global_load_dwordx4 %[w10], %[a2], off offset:128\n\t"            \
      "global_load_dwordx4 %[w11], %[a2], off offset:144\n\t"            \
      "global_load_dwordx4 %[w12], %[a3], off\n\t"                       \
      "global_load_dwordx4 %[w13], %[a3], off offset:16\n\t"             \
      "global_load_dwordx4 %[w14], %[a3], off offset:128\n\t"            \
      "global_load_dwordx4 %[w15], %[a3], off offset:144\n\t"            \
      : [w0] "=&v"(W[0]), [w1] "=&v"(W[1]), [w2] "=&v"(W[2]),            \
        [w3] "=&v"(W[3]), [w4] "=&v"(W[4]), [w5] "=&v"(W[5]),            \
        [w6] "=&v"(W[6]), [w7] "=&v"(W[7]), [w8] "=&v"(W[8]),            \
        [w9] "=&v"(W[9]), [w10] "=&v"(W[10]), [w11] "=&v"(W[11]),        \
        [w12] "=&v"(W[12]), [w13] "=&v"(W[13]), [w14] "=&v"(W[14]),      \
        [w15] "=&v"(W[15])                                               \
      : [a0] "v"(q0), [a1] "v"(q1), [a2] "v"(q2), [a3] "v"(q3)           \
      : "memory")

#define VM_WAIT32                                       \
  do {                                                  \
    asm volatile("s_waitcnt vmcnt(32)" ::: "memory");   \
    __builtin_amdgcn_sched_barrier(0);                  \
  } while (0)
#define VM_WAIT16                                       \
  do {                                                  \
    asm volatile("s_waitcnt vmcnt(16)" ::: "memory");   \
    __builtin_amdgcn_sched_barrier(0);                  \
  } while (0)
#define VM_WAIT0                                        \
  do {                                                  \
    asm volatile("s_waitcnt vmcnt(0)" ::: "memory");    \
    __builtin_amdgcn_sched_barrier(0);                  \
  } while (0)

// One 16-col tile: pack W->bf16, 8 MFMA (4 b-tiles x K64), emit 8 packed
// uint (2 per bt) for the permuted store layout.
#define TILE(W, TL, C, O0, O1, O2, O3, O4, O5, O6, O7)                        \
  do {                                                                        \
    const f32x4 A0 = (W)[(TL) * 4 + 0];                                       \
    const f32x4 A1 = (W)[(TL) * 4 + 1];                                       \
    const f32x4 A2 = (W)[(TL) * 4 + 2];                                       \
    const f32x4 A3 = (W)[(TL) * 4 + 3];                                       \
    short8 wf0, wf1;                                                          \
    wf0[0] = (short)f2bf(A0[0]); wf0[1] = (short)f2bf(A0[1]);                 \
    wf0[2] = (short)f2bf(A0[2]); wf0[3] = (short)f2bf(A0[3]);                 \
    wf0[4] = (short)f2bf(A1[0]); wf0[5] = (short)f2bf(A1[1]);                 \
    wf0[6] = (short)f2bf(A1[2]); wf0[7] = (short)f2bf(A1[3]);                 \
    wf1[0] = (short)f2bf(A2[0]); wf1[1] = (short)f2bf(A2[1]);                 \
    wf1[2] = (short)f2bf(A2[2]); wf1[3] = (short)f2bf(A2[3]);                 \
    wf1[4] = (short)f2bf(A3[0]); wf1[5] = (short)f2bf(A3[1]);                 \
    wf1[6] = (short)f2bf(A3[2]); wf1[7] = (short)f2bf(A3[3]);                 \
    float4 bf = *(const float4*)&bias_lds[wave * 256 + (C) * 64 + (TL) * 16 + \
                                          quad * 4];                          \
    f32x4 a0 = (f32x4){0.f, 0.f, 0.f, 0.f};                                   \
    f32x4 a1 = a0, a2 = a0, a3 = a0;                                          \
    a0 = __builtin_amdgcn_mfma_f32_16x16x32_bf16(wf0, uf[0][0], a0, 0, 0, 0); \
    a0 = __builtin_amdgcn_mfma_f32_16x16x32_bf16(wf1, uf[0][1], a0, 0, 0, 0); \
    a1 = __builtin_amdgcn_mfma_f32_16x16x32_bf16(wf0, uf[1][0], a1, 0, 0, 0); \
    a1 = __builtin_amdgcn_mfma_f32_16x16x32_bf16(wf1, uf[1][1], a1, 0, 0, 0); \
    a2 = __builtin_amdgcn_mfma_f32_16x16x32_bf16(wf0, uf[2][0], a2, 0, 0, 0); \
    a2 = __builtin_amdgcn_mfma_f32_16x16x32_bf16(wf1, uf[2][1], a2, 0, 0, 0); \
    a3 = __builtin_amdgcn_mfma_f32_16x16x32_bf16(wf0, uf[3][0], a3, 0, 0, 0); \
    a3 = __builtin_amdgcn_mfma_f32_16x16x32_bf16(wf1, uf[3][1], a3, 0, 0, 0); \
    O0 = f2bf(a0[0] + bf.x) | ((unsigned)f2bf(a0[1] + bf.y) << 16);           \
    O1 = f2bf(a0[2] + bf.z) | ((unsigned)f2bf(a0[3] + bf.w) << 16);           \
    O2 = f2bf(a1[0] + bf.x) | ((unsigned)f2bf(a1[1] + bf.y) << 16);           \
    O3 = f2bf(a1[2] + bf.z) | ((unsigned)f2bf(a1[3] + bf.w) << 16);           \
    O4 = f2bf(a2[0] + bf.x) | ((unsigned)f2bf(a2[1] + bf.y) << 16);           \
    O5 = f2bf(a2[2] + bf.z) | ((unsigned)f2bf(a2[3] + bf.w) << 16);           \
    O6 = f2bf(a3[0] + bf.x) | ((unsigned)f2bf(a3[1] + bf.y) << 16);           \
    O7 = f2bf(a3[2] + bf.z) | ((unsigned)f2bf(a3[3] + bf.w) << 16);           \
  } while (0)

// One chunk (4 tiles = 64 cols): per bt one 32B run per lane, stored as
// 2x global_store_dwordx4 (pairs complete full 128B lines) into the
// block-local [n][b][f'] window.
#define STEP(W, C)                                                            \
  do {                                                                        \
    u32x4 kA0, kA1, kA2, kA3, kB0, kB1, kB2, kB3;                             \
    TILE(W, 0, C, kA0.x, kA0.y, kA1.x, kA1.y, kA2.x, kA2.y, kA3.x, kA3.y);    \
    TILE(W, 1, C, kA0.z, kA0.w, kA1.z, kA1.w, kA2.z, kA2.w, kA3.z, kA3.w);    \
    TILE(W, 2, C, kB0.x, kB0.y, kB1.x, kB1.y, kB2.x, kB2.y, kB3.x, kB3.y);    \
    TILE(W, 3, C, kB0.z, kB0.w, kB1.z, kB1.w, kB2.z, kB2.w, kB3.z, kB3.w);    \
    const unsigned short* c0 = sb0 + (C) * 64;                                \
    const unsigned short* c1 = sb1 + (C) * 64;                                \
    const unsigned short* c2 = sb2 + (C) * 64;                                \
    const unsigned short* c3 = sb3 + (C) * 64;                                \
    asm volatile(                                                             \
        "global_store_dwordx4 %[a0], %[d0], off\n\t"                          \
        "global_store_dwordx4 %[a0], %[d1], off offset:16\n\t"                \
        "global_store_dwordx4 %[a1], %[d2], off\n\t"                          \
        "global_store_dwordx4 %[a1], %[d3], off offset:16\n\t"                \
        "global_store_dwordx4 %[a2], %[d4], off\n\t"                          \
        "global_store_dwordx4 %[a2], %[d5], off offset:16\n\t"                \
        "global_store_dwordx4 %[a3], %[d6], off\n\t"                          \
        "global_store_dwordx4 %[a3], %[d7], off offset:16\n\t"                \
        :: [a0] "v"(c0), [a1] "v"(c1), [a2] "v"(c2), [a3] "v"(c3),            \
           [d0] "v"(kA0), [d1] "v"(kB0), [d2] "v"(kA1), [d3] "v"(kB1),        \
           [d4] "v"(kA2), [d5] "v"(kB2), [d6] "v"(kA3), [d7] "v"(kB3)         \
        : "memory");                                                          \
  } while (0)

// K1: u_hat stored [n][b][f'] (f' permuted within 64-col blocks:
// f' = quad*16 + tile*4 + j), bf16. Grid (n, half). Wave owns 256 cols =
// 4 chunks of 64. DEPTH-3 pipeline: 3 prologue bursts, waits 32/32/16/0.
// Same proven invariants as the 433us r12 kernel: each STEP's stores
// retire in the wait preceding the next-next STEP; barrier untouched;
// VGPR ~245 fits the 2-waves/SIMD 256 cap (no launch_bounds squeeze).
__global__ __launch_bounds__(256, 2) void k_gemm(
    const float* __restrict__ u, const float* __restrict__ w,
    const float* __restrict__ bias, unsigned short* __restrict__ uhat,
    float* __restrict__ szero) {
  const int n = blockIdx.x;
  const int half = blockIdx.y;
  __shared__ __align__(16) unsigned short a_lds[64 * 72];
  __shared__ __align__(16) float bias_lds[1024];
  const int t = threadIdx.x;
  const int lane = t & 63;
  const int wave = t >> 6;
  const int row16 = lane & 15;
  const int quad = lane >> 4;

  // zero s1/s2/s3 (3*131072 floats over 2048 blocks x 192)
  {
    const int bid = half * 1024 + n;
    if (t < 192) szero[bid * 192 + t] = 0.f;
  }

  // ---- stage u[:,n,:] (bf16) + bias into LDS (all compiler VMEM here)
  {
    const int b = t >> 2;
    const int i0 = (t & 3) * 16;
    const float* src = u + (size_t)b * (NIN * IVL) + (size_t)n * IVL + i0;
    unsigned short* dst = a_lds + b * 72 + i0;
#pragma unroll
    for (int q = 0; q < 4; ++q) {
      float4 v = *(const float4*)(src + q * 4);
      dst[q * 4 + 0] = f2bf(v.x);
      dst[q * 4 + 1] = f2bf(v.y);
      dst[q * 4 + 2] = f2bf(v.z);
      dst[q * 4 + 3] = f2bf(v.w);
    }
    *(float4*)&bias_lds[t * 4] =
        *(const float4*)(bias + (size_t)n * OLSZ + half * 1024 + t * 4);
  }

  // ---- prologue bursts (chunks 0,1,2) BEFORE the barrier
  const float* wp = w + (size_t)n * (OLSZ * IVL) +
                    (size_t)(half * 1024 + wave * 256 + row16) * IVL + quad * 8;
  f32x4 bufA[16], bufB[16], bufC[16];
  W_BURST16(bufA, wp, wp + 1024, wp + 2048, wp + 3072);
  W_BURST16(bufB, wp + 4096, wp + 5120, wp + 6144, wp + 7168);
  W_BURST16(bufC, wp + 8192, wp + 9216, wp + 10240, wp + 11264);

  // manual barrier: LDS-only wait, vmcnt untouched (bursts stay in flight)
  asm volatile("s_waitcnt lgkmcnt(0)" ::: "memory");
  __builtin_amdgcn_s_barrier();

  // ---- u fragments, read once, kept in registers
  short8 uf[4][2];
#pragma unroll
  for (int bt = 0; bt < 4; ++bt) {
#pragma unroll
    for (int ks = 0; ks < 2; ++ks) {
      uf[bt][ks] =
          *(const short8*)(a_lds + (bt * 16 + row16) * 72 + ks * 32 + quad * 8);
    }
  }

  // [n][b][f'] store bases: b = bt*16 + row16 -> rows 4KB apart
  const unsigned short* sb0 = uhat + ((size_t)n * 64 + row16) * OLSZ +
                              half * 1024 + wave * 256 + quad * 16;
  const unsigned short* sb1 = sb0 + (size_t)16 * OLSZ;
  const unsigned short* sb2 = sb0 + (size_t)32 * OLSZ;
  const unsigned short* sb3 = sb0 + (size_t)48 * OLSZ;

  // ---- 4-chunk depth-3 pipelined loop
  // trace (outstanding after each wait): prologue A,B,C=48.
  // wait(32): A retired -> B,C.   STEP0 +8st; burst A'(chunk3) -> 56.
  // wait(32): B+st0 retired -> C,A'. STEP1 +8st -> 40.
  // wait(16): C+st1 retired -> A'.   STEP2 +8st -> 24.
  // wait(0):  all retired.           STEP3.
  VM_WAIT32; STEP(bufA, 0);
  W_BURST16(bufA, wp + 12288, wp + 13312, wp + 14336, wp + 15360);
  VM_WAIT32; STEP(bufB, 1);
  VM_WAIT16; STEP(bufC, 2);
  VM_WAIT0;  STEP(bufA, 3);
}

// K2: s1[b,f'] = sum_n uhat[n][b][f']. Block (b, n-chunk of 128): reads the
// full 4KB row per n, register accumulate, 8 atomics.
__global__ __launch_bounds__(256) void k_sum_n(
    const unsigned short* __restrict__ uhat, float* __restrict__ s1) {
  const int b = blockIdx.x >> 3;
  const int nc = blockIdx.x & 7;  // 8 chunks of 128 n
  const int t = threadIdx.x;
  const unsigned short* base =
      uhat + ((size_t)(nc * 128) * 64 + b) * OLSZ + t * 8;
  float acc[8];
#pragma unroll
  for (int j = 0; j < 8; ++j) acc[j] = 0.f;
#pragma unroll 4
  for (int k = 0; k < 128; ++k) {
    uint4 p = *(const uint4*)(base + (size_t)k * 64 * OLSZ);
    unsigned xs[4] = {p.x, p.y, p.z, p.w};
#pragma unroll
    for (int h = 0; h < 4; ++h) {
      acc[2 * h] += bf2f_lo(xs[h]);
      acc[2 * h + 1] += bf2f_hi(xs[h]);
    }
  }
  float* s = s1 + (size_t)b * OLSZ + t * 8;
#pragma unroll
  for (int j = 0; j < 8; ++j) atomicAdd(s + j, acc[j]);
}

// K3/K4: one routing iteration on the permuted [n][b][f'] layout, b1-free.
// NO launch_bounds min-waves (r15: capping below natural VGPR -> remat+spill).
__global__ __launch_bounds__(256) void k_route(
    const unsigned short* __restrict__ uhat, const float* __restrict__ svA,
    float scaleA, const float* __restrict__ svB, float scaleB, int useB,
    float* __restrict__ sout) {
  const int b = blockIdx.x >> 5;
  const int chunk = blockIdx.x & 31;
  const int t = threadIdx.x;
  const int lane = t & 63;
  const int wave = t >> 6;
  __shared__ float red[4][OLSZ];  // 32 KB

  float v[4][8];
#pragma unroll
  for (int q = 0; q < 4; ++q) {
    const float* svp = svA + (size_t)b * OLSZ + q * 512 + lane * 8;
    float4 a0 = *(const float4*)svp;
    float4 a1 = *(const float4*)(svp + 4);
    v[q][0] = a0.x * scaleA; v[q][1] = a0.y * scaleA;
    v[q][2] = a0.z * scaleA; v[q][3] = a0.w * scaleA;
    v[q][4] = a1.x * scaleA; v[q][5] = a1.y * scaleA;
    v[q][6] = a1.z * scaleA; v[q][7] = a1.w * scaleA;
    float p = 0.f;
#pragma unroll
    for (int j = 0; j < 8; ++j) p = fmaf(v[q][j], v[q][j], p);
    p += __shfl_xor(p, 2);
    p += __shfl_xor(p, 4);
    float f = p / ((1.f + p) * (sqrtf(p) + 1e-5f));
#pragma unroll
    for (int j = 0; j < 8; ++j) v[q][j] *= f;
  }
  if (useB) {
#pragma unroll
    for (int q = 0; q < 4; ++q) {
      const float* svp = svB + (size_t)b * OLSZ + q * 512 + lane * 8;
      float4 a0 = *(const float4*)svp;
      float4 a1 = *(const float4*)(svp + 4);
      float w2[8];
      w2[0] = a0.x * scaleB; w2[1] = a0.y * scaleB;
      w2[2] = a0.z * scaleB; w2[3] = a0.w * scaleB;
      w2[4] = a1.x * scaleB; w2[5] = a1.y * scaleB;
      w2[6] = a1.z * scaleB; w2[7] = a1.w * scaleB;
      float p = 0.f;
#pragma unroll
      for (int j = 0; j < 8; ++j) p = fmaf(w2[j], w2[j], p);
      p += __shfl_xor(p, 2);
      p += __shfl_xor(p, 4);
      float f = p / ((1.f + p) * (sqrtf(p) + 1e-5f));
#pragma unroll
      for (int j = 0; j < 8; ++j) v[q][j] = fmaf(w2[j], f, v[q][j]);
    }
  }

  float racc[4][8];
#pragma unroll
  for (int q = 0; q < 4; ++q)
#pragma unroll
    for (int j = 0; j < 8; ++j) racc[q][j] = 0.f;

  const int n0 = chunk * 32 + wave * 8;
  const unsigned short* ub = uhat + ((size_t)n0 * 64 + b) * OLSZ + lane * 8;
  const size_t NSTRIDE = (size_t)64 * OLSZ;  // one n step in [n][b][f']

  uint4 pA[4], pB[4];
#pragma unroll
  for (int q = 0; q < 4; ++q) pA[q] = *(const uint4*)(ub + q * 512);

  auto process = [&](const uint4(&pk)[4]) {
    float ud[4][8];
    float d[4];
#pragma unroll
    for (int q = 0; q < 4; ++q) {
      unsigned xs[4] = {pk[q].x, pk[q].y, pk[q].z, pk[q].w};
#pragma unroll
      for (int h = 0; h < 4; ++h) {
        ud[q][2 * h] = bf2f_lo(xs[h]);
        ud[q][2 * h + 1] = bf2f_hi(xs[h]);
      }
      float p = 0.f;
#pragma unroll
      for (int j = 0; j < 8; ++j) p = fmaf(ud[q][j], v[q][j], p);
      p += __shfl_xor(p, 2);  // reduce over same-o lane group
      p += __shfl_xor(p, 4);
      d[q] = p;
    }
    // softmax over all 64 o: xor levels 1,8,16,32 cover each o once.
    float m = fmaxf(fmaxf(d[0], d[1]), fmaxf(d[2], d[3]));
    m = fmaxf(m, __shfl_xor(m, 1));
    m = fmaxf(m, __shfl_xor(m, 8));
    m = fmaxf(m, __shfl_xor(m, 16));
    m = fmaxf(m, __shfl_xor(m, 32));
    float e0 = __expf(d[0] - m);
    float e1 = __expf(d[1] - m);
    float e2 = __expf(d[2] - m);
    float e3 = __expf(d[3] - m);
    float ls = (e0 + e1) + (e2 + e3);
    ls += __shfl_xor(ls, 1);
    ls += __shfl_xor(ls, 8);
    ls += __shfl_xor(ls, 16);
    ls += __shfl_xor(ls, 32);
    float inv = 1.0f / ls;
    float c[4] = {e0 * inv, e1 * inv, e2 * inv, e3 * inv};
#pragma unroll
    for (int q = 0; q < 4; ++q) {
#pragma unroll
      for (int j = 0; j < 8; ++j)
        racc[q][j] = fmaf(c[q], ud[q][j], racc[q][j]);
    }
  };

#pragma unroll
  for (int kk = 0; kk < 4; ++kk) {
    {
#pragma unroll
      for (int q = 0; q < 4; ++q)
        pB[q] = *(const uint4*)(ub + (size_t)(2 * kk + 1) * NSTRIDE + q * 512);
    }
    process(pA);
    if (2 * kk + 2 < 8) {
#pragma unroll
      for (int q = 0; q < 4; ++q)
        pA[q] = *(const uint4*)(ub + (size_t)(2 * kk + 2) * NSTRIDE + q * 512);
    }
    process(pB);
  }

#pragma unroll
  for (int q = 0; q < 4; ++q) {
    float* dst = &red[wave][q * 512 + lane * 8];
    *(float4*)(dst) =
        make_float4(racc[q][0], racc[q][1], racc[q][2], racc[q][3]);
    *(float4*)(dst + 4) =
        make_float4(racc[q][4], racc[q][5], racc[q][6], racc[q][7]);
  }
  __syncthreads();
  float* so = sout + (size_t)b * OLSZ;
#pragma unroll
  for (int j = 0; j < 8; ++j) {
    const int idx = t + 256 * j;
    float s = (red[0][idx] + red[1][idx]) + (red[2][idx] + red[3][idx]);
    atomicAdd(so + idx, s);
  }
}

// K5: out = squash(s3). s3 is permuted; out must be original layout.
__global__ __launch_bounds__(256) void k_final(const float* __restrict__ s3,
                                               float* __restrict__ out) {
  const int b = blockIdx.x;
  const int t = threadIdx.x;
  __shared__ float norm2[64];
  if (t < 64) norm2[t] = 0.f;
  __syncthreads();
  float scv[8];
#pragma unroll
  for (int k = 0; k < 8; ++k) {
    int idx = t + k * 256;
    float sc = s3[b * OLSZ + idx];
    scv[k] = sc;
    int o = ((idx >> 9) << 4) + (((idx >> 6) & 7) << 1) + ((idx >> 3) & 1);
    atomicAdd(&norm2[o], sc * sc);
  }
  __syncthreads();
#pragma unroll
  for (int k = 0; k < 8; ++k) {
    int idx = t + k * 256;
    int o = ((idx >> 9) << 4) + (((idx >> 6) & 7) << 1) + ((idx >> 3) & 1);
    float n2 = norm2[o];
    float f = n2 / ((1.f + n2) * (sqrtf(n2) + 1e-5f));
    int q2 = (idx >> 4) & 3;  // quad within 64-block
    int t2 = (idx >> 2) & 3;  // tile within 64-block
    int j = idx & 3;
    int fr = (idx & ~63) | (t2 << 4) | (q2 << 2) | j;  // un-permute
    out[b * OLSZ + fr] = scv[k] * f;
  }
}

extern "C" void kernel_launch(void* const* d_in, const int* in_sizes, int n_in,
                              void* d_out, int out_size, void* d_ws,
                              size_t ws_size, hipStream_t stream) {
  const float* u = (const float*)d_in[0];
  const float* w = (const float*)d_in[1];
  const float* bias = (const float*)d_in[2];
  float* out = (float*)d_out;

  char* ws = (char*)d_ws;
  unsigned short* uhat = (unsigned short*)ws;                 // 268435456 B
  float* s1 = (float*)(ws + (size_t)268435456);               // 524288 B
  float* s2 = s1 + 131072;                                    // 524288 B
  float* s3 = s2 + 131072;                                    // 524288 B

  // s1/s2/s3 zeroed inside k_gemm (no hipMemsetAsync in the hot path)
  k_gemm<<<dim3(1024, 2), dim3(256), 0, stream>>>(u, w, bias, uhat, s1);
  k_sum_n<<<dim3(512), dim3(256), 0, stream>>>(uhat, s1);
  // iter 1: v1 = squash(s1/64)
  k_route<<<dim3(2048), dim3(256), 0, stream>>>(uhat, s1, 1.0f / 64.0f,
                                                (const float*)nullptr, 0.f, 0, s2);
  // iter 2: bno = dot(ud, v1 + v2), v2 = squash(s2)
  k_route<<<dim3(2048), dim3(256), 0, stream>>>(uhat, s1, 1.0f / 64.0f,
                                                s2, 1.0f, 1, s3);
  k_final<<<dim3(64), dim3(256), 0, stream>>>(s3, out);
}